// Round 3
// baseline (447.439 us; speedup 1.0000x reference)
//
#include <hip/hip_runtime.h>
#include <hip/hip_bf16.h>

// Problem constants
#define Bsz 4
#define Tsz 2048
#define Dsz 1024
#define Ssz 16
#define Esz 2048
#define Mrows (Bsz*Tsz)        // 8192

typedef __attribute__((ext_vector_type(8))) short short8;
typedef __attribute__((ext_vector_type(4))) float floatx4;
typedef __attribute__((ext_vector_type(8))) int int8v;
typedef __attribute__((ext_vector_type(4))) int int4v;

__device__ __forceinline__ void async_ld16(const void* g, void* l) {
    __builtin_amdgcn_global_load_lds(
        (const __attribute__((address_space(1))) void*)g,
        (__attribute__((address_space(3))) void*)l,
        16, 0, 0);
}

__device__ __forceinline__ float sigmoidf_(float v) { return 1.f / (1.f + expf(-v)); }
__device__ __forceinline__ float bf2f(unsigned short u) {
    union { unsigned u32; float f; } c; c.u32 = (unsigned)u << 16; return c.f;
}
__device__ __forceinline__ int pk_fp8x4(float a, float b, float c, float d) {
    int lo = __builtin_amdgcn_cvt_pk_fp8_f32(a, b, 0, 0);
    int hi = __builtin_amdgcn_cvt_pk_fp8_f32(c, d, 0, 0);
    return (lo & 0xFFFF) | (hi << 16);
}

// s_waitcnt immediates (gfx9): vm[3:0]|exp[6:4]|lgkm[11:8]|vm[15:14]
#define WAIT_VM(N)   (0xF70 | (N))

// ---------------------------------------------------------------------------
// merged conversions: x -> fp8 (x1), in_w -> fp8 (x64), dt_w -> fp8 (x64),
// out_w -> fp8 (x64).
// ---------------------------------------------------------------------------
#define CV_S0 2097152   // x:     8388608 f32 / 4
#define CV_S1 3145728   // in_w: +4194304 / 4
#define CV_S2 4194304   // dt_w: +4194304 / 4
#define CV_S3 4718592   // out_w:+2097152 / 4
__global__ void cvt_all(const float4* __restrict__ x,  const float4* __restrict__ iw,
                        const float4* __restrict__ dw, const float4* __restrict__ ow,
                        int* __restrict__ x8, int* __restrict__ iw8,
                        int* __restrict__ dw8, int* __restrict__ ow8) {
    int i = blockIdx.x * blockDim.x + threadIdx.x;
    const int stride = gridDim.x * blockDim.x;
    for (; i < CV_S3; i += stride) {
        if (i < CV_S0) {
            float4 v = x[i];
            x8[i] = pk_fp8x4(v.x, v.y, v.z, v.w);
        } else if (i < CV_S1) {
            const int j = i - CV_S0;
            float4 v = iw[j];
            iw8[j] = pk_fp8x4(v.x * 64.f, v.y * 64.f, v.z * 64.f, v.w * 64.f);
        } else if (i < CV_S2) {
            const int j = i - CV_S1;
            float4 v = dw[j];
            dw8[j] = pk_fp8x4(v.x * 64.f, v.y * 64.f, v.z * 64.f, v.w * 64.f);
        } else {
            const int j = i - CV_S2;
            float4 v = ow[j];
            ow8[j] = pk_fp8x4(v.x * 64.f, v.y * 64.f, v.z * 64.f, v.w * 64.f);
        }
    }
}

// ---------------------------------------------------------------------------
// 256x256 8-wave 4-phase MX-fp8 GEMM (T3+T4+T5 port of the 8-phase template).
// R3: three 128-tile 2-phase variants all hit the documented 2-phase wall
// (~607 TF, m233); escape = phase-split K-step + counted vmcnt + setprio.
// Geometry: BM=BN=256, BK=128B, 512 thr (8 waves 2Mx4N), wave tile 128x64,
// acc 8x4 x floatx4 (128 AGPR).  LDS 2 stages x (A 32KB + B 32KB) = 128KB,
// 1 block/CU, 2 waves/SIMD.
// Per K-tile: 4 phases; phase p: {issue 2 staging loads for tile kt+1;
// ds_read A-frag pair 2p,2p+1; setprio(1); 8 mfma_scale; setprio(0)}.
// Load FIFO per tile: B0,B1 | B2,B3 | A0,A2 | A1,A3  (A-round r = rows
// [64r,64r+64); frags 0-3 need rounds {0,2}, frags 4-7 rounds {1,3}).
// Waits: ph0 vmcnt(2) certifies B*+A0+A2 of tile kt (leaves A1,A3);
// ph2 vmcnt(4) certifies A1,A3 (leaves next tile's B0..B3).  Barrier after
// each wait publishes certification to all waves before dependent ds_reads.
// Issues target stage (kt+1)&1, never the stage being read -> race-free.
// MODE: 0 bf16 store, 1 softplus rowsum.
// ---------------------------------------------------------------------------
template<int MODE, int SA, int SB, int K, int N>
__launch_bounds__(512, 2)
__global__ void gemm256(const unsigned char* __restrict__ A,
                        const unsigned char* __restrict__ Bw,
                        const float* __restrict__ bias,
                        __hip_bfloat16* __restrict__ outb,
                        float* __restrict__ rowsum) {
    __shared__ __align__(16) unsigned char sA[2 * 32768];  // 256 rows x 128B
    __shared__ __align__(16) unsigned char sB[2 * 32768];

    const int tid  = threadIdx.x;
    const int wave = tid >> 6, lane = tid & 63;
    const int wm = wave >> 2, wn = wave & 3;       // 2 x 4 wave grid
    const int q = lane >> 4, lr = lane & 15;

    // XCD-aware remap: gy = 32 -> stripe 4 per XCD; nwg % 8 == 0 (bijective).
    const int gx = gridDim.x;
    const int flat = blockIdx.y * gx + blockIdx.x;
    const int xcd = flat & 7, local = flat >> 3;
    const int mt = xcd * 4 + (local & 3);
    const int nt = local >> 2;
    const int m0 = mt * 256, n0 = nt * 256;

    floatx4 acc[8][4];
#pragma unroll
    for (int i = 0; i < 8; ++i)
#pragma unroll
        for (int j = 0; j < 4; ++j) acc[i][j] = (floatx4){0.f, 0.f, 0.f, 0.f};

    // staging: round r covers rows [64r, 64r+64); wave w rows 64r+8w..+7.
    // LDS slot s of row holds global 16B chunk s^(row&7); row&7 == lane>>3.
    const int rowin = lane >> 3;                   // row within wave's 8
    const int chunk = (lane & 7) ^ rowin;
    const unsigned char* pa = A  + (size_t)(m0 + wave * 8 + rowin) * K + chunk * 16;
    const unsigned char* pb = Bw + (size_t)(n0 + wave * 8 + rowin) * K + chunk * 16;
    const int ldsw = wave * 8 * 128;               // wave base within a round

    // fragment read offsets: A-frag f row = wm*128 + f*16 + lr  (row&7 = lr&7)
    const int c0 = ((2 * q)     ^ (lr & 7)) * 16;
    const int c1 = ((2 * q + 1) ^ (lr & 7)) * 16;
    const int oA = (wm * 128 + lr) * 128;          // + f*2048
    const int oB = (wn * 64  + lr) * 128;          // + g*2048

#define G256_ISSUE_B(r) async_ld16(pb + (size_t)(r) * 64 * K + koff, \
                                   &sB[sbo + ((r) * 64 * 128) + ldsw])
#define G256_ISSUE_A(r) async_ld16(pa + (size_t)(r) * 64 * K + koff, \
                                   &sA[sbo + ((r) * 64 * 128) + ldsw])
#define G256_RD(dst, base, off) do {                                        \
        int4v lo_ = *(const int4v*)&(base)[(off) + c0];                     \
        int4v hi_ = *(const int4v*)&(base)[(off) + c1];                     \
        dst = __builtin_shufflevector(lo_, hi_, 0, 1, 2, 3, 4, 5, 6, 7);    \
    } while (0)

    // prologue: tile 0 in FIFO order B0,B1,B2,B3,A0,A2,A1,A3 -> stage 0
    {
        const size_t koff = 0; const int sbo = 0;
        G256_ISSUE_B(0); G256_ISSUE_B(1); G256_ISSUE_B(2); G256_ISSUE_B(3);
        G256_ISSUE_A(0); G256_ISSUE_A(2); G256_ISSUE_A(1); G256_ISSUE_A(3);
    }

    const int NT = K >> 7;
    for (int kt = 0; kt < NT; ++kt) {
        const int sb  = (kt & 1) * 32768;
        const int sbo = ((kt + 1) & 1) * 32768;
        const size_t koff = (size_t)(kt + 1) * 128;

        // ---- phase 0: B* + A-frags 0,1 (rounds 0/2 certified) ----
        __builtin_amdgcn_s_waitcnt(WAIT_VM(2));
        __builtin_amdgcn_s_barrier();
        G256_ISSUE_B(0); G256_ISSUE_B(1);
        int8v b8[4];
#pragma unroll
        for (int g = 0; g < 4; ++g) G256_RD(b8[g], &sB[sb], oB + g * 2048);
        {
            int8v a0, a1;
            G256_RD(a0, &sA[sb], oA + 0 * 2048);
            G256_RD(a1, &sA[sb], oA + 1 * 2048);
            __builtin_amdgcn_s_setprio(1);
#pragma unroll
            for (int g = 0; g < 4; ++g) {
                acc[0][g] = __builtin_amdgcn_mfma_scale_f32_16x16x128_f8f6f4(
                    a0, b8[g], acc[0][g], 0, 0, 0, SA, 0, SB);
                acc[1][g] = __builtin_amdgcn_mfma_scale_f32_16x16x128_f8f6f4(
                    a1, b8[g], acc[1][g], 0, 0, 0, SA, 0, SB);
            }
            __builtin_amdgcn_s_setprio(0);
        }
        // ---- phase 1: A-frags 2,3 ----
        G256_ISSUE_B(2); G256_ISSUE_B(3);
        {
            int8v a0, a1;
            G256_RD(a0, &sA[sb], oA + 2 * 2048);
            G256_RD(a1, &sA[sb], oA + 3 * 2048);
            __builtin_amdgcn_s_setprio(1);
#pragma unroll
            for (int g = 0; g < 4; ++g) {
                acc[2][g] = __builtin_amdgcn_mfma_scale_f32_16x16x128_f8f6f4(
                    a0, b8[g], acc[2][g], 0, 0, 0, SA, 0, SB);
                acc[3][g] = __builtin_amdgcn_mfma_scale_f32_16x16x128_f8f6f4(
                    a1, b8[g], acc[3][g], 0, 0, 0, SA, 0, SB);
            }
            __builtin_amdgcn_s_setprio(0);
        }
        // ---- phase 2: A-frags 4,5 (rounds 1/3 certified) ----
        __builtin_amdgcn_s_waitcnt(WAIT_VM(4));
        __builtin_amdgcn_s_barrier();
        G256_ISSUE_A(0); G256_ISSUE_A(2);
        {
            int8v a0, a1;
            G256_RD(a0, &sA[sb], oA + 4 * 2048);
            G256_RD(a1, &sA[sb], oA + 5 * 2048);
            __builtin_amdgcn_s_setprio(1);
#pragma unroll
            for (int g = 0; g < 4; ++g) {
                acc[4][g] = __builtin_amdgcn_mfma_scale_f32_16x16x128_f8f6f4(
                    a0, b8[g], acc[4][g], 0, 0, 0, SA, 0, SB);
                acc[5][g] = __builtin_amdgcn_mfma_scale_f32_16x16x128_f8f6f4(
                    a1, b8[g], acc[5][g], 0, 0, 0, SA, 0, SB);
            }
            __builtin_amdgcn_s_setprio(0);
        }
        // ---- phase 3: A-frags 6,7 ----
        G256_ISSUE_A(1); G256_ISSUE_A(3);
        {
            int8v a0, a1;
            G256_RD(a0, &sA[sb], oA + 6 * 2048);
            G256_RD(a1, &sA[sb], oA + 7 * 2048);
            __builtin_amdgcn_s_setprio(1);
#pragma unroll
            for (int g = 0; g < 4; ++g) {
                acc[6][g] = __builtin_amdgcn_mfma_scale_f32_16x16x128_f8f6f4(
                    a0, b8[g], acc[6][g], 0, 0, 0, SA, 0, SB);
                acc[7][g] = __builtin_amdgcn_mfma_scale_f32_16x16x128_f8f6f4(
                    a1, b8[g], acc[7][g], 0, 0, 0, SA, 0, SB);
            }
            __builtin_amdgcn_s_setprio(0);
        }
    }
#undef G256_ISSUE_B
#undef G256_ISSUE_A
#undef G256_RD
    __builtin_amdgcn_s_waitcnt(WAIT_VM(0));   // drain garbage tail tile

    // epilogue: C/D col = lane&15, row = (lane>>4)*4 + reg
    if (MODE == 0) {
#pragma unroll
        for (int i = 0; i < 8; ++i) {
            const int row = m0 + wm * 128 + i * 16 + q * 4;
#pragma unroll
            for (int j = 0; j < 4; ++j) {
                const int col = n0 + wn * 64 + j * 16 + lr;
                const float bc = bias[col];
#pragma unroll
                for (int r = 0; r < 4; ++r)
                    outb[(size_t)(row + r) * N + col] = __float2bfloat16(acc[i][j][r] + bc);
            }
        }
    } else {
#pragma unroll
        for (int i = 0; i < 8; ++i) {
            float rs[4] = {0.f, 0.f, 0.f, 0.f};
#pragma unroll
            for (int j = 0; j < 4; ++j) {
                const int col = n0 + wn * 64 + j * 16 + lr;
                const float bc = bias[col];
#pragma unroll
                for (int r = 0; r < 4; ++r) {
                    float v = acc[i][j][r] + bc;
                    float sp = (v > 20.f) ? v : log1pf(expf(v));
                    rs[r] += sp;
                }
            }
#pragma unroll
            for (int r = 0; r < 4; ++r) {
                float v = rs[r];
                v += __shfl_xor(v, 1); v += __shfl_xor(v, 2);
                v += __shfl_xor(v, 4); v += __shfl_xor(v, 8);
                if (lr == 0)
                    atomicAdd(&rowsum[m0 + wm * 128 + i * 16 + q * 4 + r], v);
            }
        }
    }
}

// ---------------------------------------------------------------------------
// 128x128 2-phase MX-fp8 GEMM (proven R2 loop) — kept for GEMM3 (N=1024,
// only 128 big tiles would idle half the machine at 256²).
// MODE 2 only: fp32 resid + ys[row]*acc + bias.
// ---------------------------------------------------------------------------
template<int SA, int SB>
__launch_bounds__(256, 2)
__global__ void gemm_f8_sm(const unsigned char* __restrict__ A,
                           const unsigned char* __restrict__ Bw,
                           const float* __restrict__ bias,
                           int M, int N, int K,
                           const float* __restrict__ resid,
                           const float* __restrict__ ysv,
                           float* __restrict__ outf) {
    __shared__ __align__(16) unsigned char sA[2 * 16384];
    __shared__ __align__(16) unsigned char sB[2 * 16384];

    const int tid  = threadIdx.x;
    const int wave = tid >> 6, lane = tid & 63;
    const int wm = wave >> 1, wn = wave & 1;
    const int q = lane >> 4, lr = lane & 15;

    const int gx = gridDim.x, gy = gridDim.y;
    const int flat = blockIdx.y * gx + blockIdx.x;
    const int stripe = gy >> 3;
    const int xcd = flat & 7, local = flat >> 3;
    const int mt = xcd * stripe + (local % stripe);
    const int nt = local / stripe;
    const int m0 = mt * 128, n0 = nt * 128;

    floatx4 acc[4][4];
#pragma unroll
    for (int i = 0; i < 4; ++i)
#pragma unroll
        for (int j = 0; j < 4; ++j) acc[i][j] = (floatx4){0.f, 0.f, 0.f, 0.f};

    const unsigned char* pa[4];
    const unsigned char* pb[4];
#pragma unroll
    for (int i = 0; i < 4; ++i) {
        const int idx = i * 256 + tid, row = idx >> 3, s = idx & 7;
        pa[i] = A + (size_t)(m0 + row) * K + ((s ^ (row & 7)) * 16);
        pb[i] = Bw + (size_t)(n0 + row) * K + ((s ^ (row & 7)) * 16);
    }

    const int rA = wm * 64 + lr, rB = wn * 64 + lr;
    const int oA0 = rA * 128 + (((2 * q)     ^ (rA & 7)) * 16);
    const int oA1 = rA * 128 + (((2 * q + 1) ^ (rA & 7)) * 16);
    const int oB0 = rB * 128 + (((2 * q)     ^ (rB & 7)) * 16);
    const int oB1 = rB * 128 + (((2 * q + 1) ^ (rB & 7)) * 16);

#define F8_ISSUE(ST) do {                                                      \
        _Pragma("unroll")                                                      \
        for (int i = 0; i < 4; ++i) {                                          \
            async_ld16(pa[i], &sA[(ST) * 16384 + (i * 256 + wave * 64) * 16]); \
            pa[i] += 128;                                                      \
        }                                                                      \
        _Pragma("unroll")                                                      \
        for (int i = 0; i < 4; ++i) {                                          \
            async_ld16(pb[i], &sB[(ST) * 16384 + (i * 256 + wave * 64) * 16]); \
            pb[i] += 128;                                                      \
        }                                                                      \
    } while (0)

    const int ntile = K >> 7;
    F8_ISSUE(0);
    for (int kt = 0; kt < ntile; ++kt) {
        const int st = kt & 1;
        __builtin_amdgcn_s_waitcnt(WAIT_VM(0));
        __syncthreads();
        F8_ISSUE(st ^ 1);

        int8v a8[4], b8[4];
#pragma unroll
        for (int i = 0; i < 4; ++i) {
            int4v lo = *(const int4v*)&sA[st * 16384 + oA0 + i * 2048];
            int4v hi = *(const int4v*)&sA[st * 16384 + oA1 + i * 2048];
            a8[i] = __builtin_shufflevector(lo, hi, 0, 1, 2, 3, 4, 5, 6, 7);
        }
#pragma unroll
        for (int j = 0; j < 4; ++j) {
            int4v lo = *(const int4v*)&sB[st * 16384 + oB0 + j * 2048];
            int4v hi = *(const int4v*)&sB[st * 16384 + oB1 + j * 2048];
            b8[j] = __builtin_shufflevector(lo, hi, 0, 1, 2, 3, 4, 5, 6, 7);
        }
#pragma unroll
        for (int i = 0; i < 4; ++i)
#pragma unroll
            for (int j = 0; j < 4; ++j)
                acc[i][j] = __builtin_amdgcn_mfma_scale_f32_16x16x128_f8f6f4(
                    a8[i], b8[j], acc[i][j], 0, 0, 0, SA, 0, SB);
    }
#undef F8_ISSUE
    __builtin_amdgcn_s_waitcnt(WAIT_VM(0));

#pragma unroll
    for (int i = 0; i < 4; ++i) {
        const int row = m0 + wm * 64 + i * 16 + q * 4;
#pragma unroll
        for (int j = 0; j < 4; ++j) {
            const int col = n0 + wn * 64 + j * 16 + lr;
            const float bc = bias[col];
#pragma unroll
            for (int r = 0; r < 4; ++r) {
                const size_t idx = (size_t)(row + r) * N + col;
                outf[idx] = resid[idx] + ysv[row + r] * acc[i][j][r] + bc;
            }
        }
    }
}

// ---------------------------------------------------------------------------
// fused elementwise pass over xp: depthwise conv(k=3)+bias+SiLU on main half
// -> xc (bf16) + xc*16 (fp8); SiLU on gate half -> S*16 (fp8).
// ---------------------------------------------------------------------------
__global__ void conv_gate_k(const __hip_bfloat16* __restrict__ xp,
                            const float* __restrict__ cw,
                            const float* __restrict__ cb,
                            __hip_bfloat16* __restrict__ xc,
                            int2* __restrict__ xc8,
                            int2* __restrict__ s8) {
    const int idx8 = blockIdx.x * blockDim.x + threadIdx.x;
    const int e = (idx8 & (Esz / 8 - 1)) * 8;
    const int r = idx8 >> 8;
    const int t = r & (Tsz - 1);
    const unsigned short* row0 = (const unsigned short*)(xp + (size_t)r * (2 * Esz) + e);
    short8 vm1 = (t > 0)       ? *(const short8*)(row0 - 2 * Esz) : (short8){0,0,0,0,0,0,0,0};
    short8 v00 = *(const short8*)row0;
    short8 vp1 = (t < Tsz - 1) ? *(const short8*)(row0 + 2 * Esz) : (short8){0,0,0,0,0,0,0,0};
    short8 o;
    float sil[8];
#pragma unroll
    for (int k = 0; k < 8; ++k) {
        const int ek = e + k;
        float v = bf2f((unsigned short)vm1[k]) * cw[ek * 3 + 0]
                + bf2f((unsigned short)v00[k]) * cw[ek * 3 + 1]
                + bf2f((unsigned short)vp1[k]) * cw[ek * 3 + 2] + cb[ek];
        sil[k] = v * sigmoidf_(v);
        __hip_bfloat16 h = __float2bfloat16(sil[k]);
        o[k] = *(short*)&h;
    }
    *(short8*)(xc + (size_t)idx8 * 8) = o;
    int2 p;
    p.x = pk_fp8x4(sil[0] * 16.f, sil[1] * 16.f, sil[2] * 16.f, sil[3] * 16.f);
    p.y = pk_fp8x4(sil[4] * 16.f, sil[5] * 16.f, sil[6] * 16.f, sil[7] * 16.f);
    xc8[idx8] = p;

    short8 g = *(const short8*)(row0 + Esz);
    float sg[8];
#pragma unroll
    for (int k = 0; k < 8; ++k) {
        const float gv = bf2f((unsigned short)g[k]);
        sg[k] = gv * sigmoidf_(gv);
    }
    int2 ps;
    ps.x = pk_fp8x4(sg[0] * 16.f, sg[1] * 16.f, sg[2] * 16.f, sg[3] * 16.f);
    ps.y = pk_fp8x4(sg[4] * 16.f, sg[5] * 16.f, sg[6] * 16.f, sg[7] * 16.f);
    s8[idx8] = ps;
}

// ---------------------------------------------------------------------------
// pack B_w/C_w/D_w (each [16,2048] fp32) into Wb [48,2048] bf16
// ---------------------------------------------------------------------------
__global__ void pack_bcd(const float* __restrict__ Bw, const float* __restrict__ Cw,
                         const float* __restrict__ Dw, __hip_bfloat16* __restrict__ Wb) {
    const int idx = blockIdx.x * blockDim.x + threadIdx.x;
    if (idx >= 48 * Esz) return;
    const int row = idx >> 11, col = idx & (Esz - 1);
    float v;
    if (row < 16)      v = Bw[row * Esz + col];
    else if (row < 32) v = Cw[(row - 16) * Esz + col];
    else               v = Dw[(row - 32) * Esz + col];
    Wb[idx] = __float2bfloat16(v);
}

// ---------------------------------------------------------------------------
// B/C/D projections via MFMA skinny GEMM: xc[M,E] @ Wb[48,E]^T.
// ---------------------------------------------------------------------------
__launch_bounds__(256)
__global__ void bcd_mfma(const __hip_bfloat16* __restrict__ xc,
                         const __hip_bfloat16* __restrict__ Wb,
                         const float* __restrict__ Bb, const float* __restrict__ Cb,
                         const float* __restrict__ Db,
                         float* __restrict__ u, float* __restrict__ Ct) {
    __shared__ __align__(16) __hip_bfloat16 sA[64 * 32];
    __shared__ __align__(16) __hip_bfloat16 sW[48 * 32];
    const int tid = threadIdx.x;
    const int wave = tid >> 6, lane = tid & 63;
    const int q = lane >> 4, lr = lane & 15;
    const int m0 = blockIdx.x * 64;

    floatx4 acc[3];
#pragma unroll
    for (int j = 0; j < 3; ++j) acc[j] = (floatx4){0.f, 0.f, 0.f, 0.f};

    const int ra = wave * 16 + (lane >> 2);
    const int ca = (lane & 3) * 8;

    for (int kt = 0; kt < (Esz >> 5); ++kt) {
        const int k0 = kt << 5;
        __syncthreads();
        async_ld16(&xc[(size_t)(m0 + ra) * Esz + k0 + ca], &sA[wave * 512]);
        if (wave < 3)
            async_ld16(&Wb[(size_t)ra * Esz + k0 + ca], &sW[wave * 512]);
        __syncthreads();

        short8 af = *(const short8*)&sA[(wave * 16 + lr) * 32 + q * 8];
#pragma unroll
        for (int j = 0; j < 3; ++j) {
            short8 wf = *(const short8*)&sW[(j * 16 + lr) * 32 + q * 8];
            acc[j] = __builtin_amdgcn_mfma_f32_16x16x32_bf16(af, wf, acc[j], 0, 0, 0);
        }
    }

    const int row = m0 + wave * 16 + q * 4;
    const float bb = Bb[lr], cbv = Cb[lr], db = Db[lr];
#pragma unroll
    for (int r = 0; r < 4; ++r) {
        const float bt = acc[0][r] + bb;
        const float ct = acc[1][r] + cbv;
        const float dt = acc[2][r] + db;
        u [(size_t)(row + r) * Ssz + lr] = bt * dt;
        Ct[(size_t)(row + r) * Ssz + lr] = ct;
    }
}

// ---------------------------------------------------------------------------
// Sequential SSM scan (decay computed inline from rowsum).  One block/batch.
// ---------------------------------------------------------------------------
__global__ void scan_k(const float* __restrict__ rowsum, const float* __restrict__ u,
                       const float* __restrict__ Ct, float* __restrict__ ys) {
    const int b = blockIdx.x;
    const int tid = threadIdx.x;
    const int lane = tid & 63, wave = tid >> 6;
    __shared__ __align__(16) float su[256 * Ssz];
    __shared__ __align__(16) float sc[256 * Ssz];
    __shared__ float sp[256 * 17];
    __shared__ float sd[256];
    float st = 0.f;
    for (int t0 = 0; t0 < Tsz; t0 += 256) {
        __syncthreads();
        const float4* ub = (const float4*)(u  + ((size_t)b * Tsz + t0) * Ssz);
        const float4* cb = (const float4*)(Ct + ((size_t)b * Tsz + t0) * Ssz);
#pragma unroll
        for (int i = 0; i < 4; ++i) {
            ((float4*)su)[tid + i * 256] = ub[tid + i * 256];
            ((float4*)sc)[tid + i * 256] = cb[tid + i * 256];
        }
        {
            const float m = rowsum[b * Tsz + t0 + tid] * (1.f / (float)Esz);
            sd[tid] = expf(fminf(fmaxf(-m, -10.f), 10.f));
        }
        __syncthreads();
        if (wave == 0 && lane < 16) {
#pragma unroll 8
            for (int i = 0; i < 256; ++i) {
                st = st * sd[i] + su[i * Ssz + lane];
                sp[i * 17 + lane] = sc[i * Ssz + lane] * st;
            }
        }
        __syncthreads();
        float s = 0.f;
#pragma unroll
        for (int j = 0; j < 16; ++j) s += sp[tid * 17 + j];
        ys[b * Tsz + t0 + tid] = s;
    }
}

// ---------------------------------------------------------------------------
extern "C" void kernel_launch(void* const* d_in, const int* in_sizes, int n_in,
                              void* d_out, int out_size, void* d_ws, size_t ws_size,
                              hipStream_t stream) {
    const float* x      = (const float*)d_in[0];
    const float* in_w   = (const float*)d_in[1];
    const float* in_b   = (const float*)d_in[2];
    const float* conv_w = (const float*)d_in[3];
    const float* conv_b = (const float*)d_in[4];
    const float* dt_w   = (const float*)d_in[5];
    const float* dt_b   = (const float*)d_in[6];
    const float* B_w    = (const float*)d_in[7];
    const float* B_b    = (const float*)d_in[8];
    const float* C_w    = (const float*)d_in[9];
    const float* C_b    = (const float*)d_in[10];
    const float* D_w    = (const float*)d_in[11];
    const float* D_b    = (const float*)d_in[12];
    const float* out_w  = (const float*)d_in[13];
    const float* out_b  = (const float*)d_in[14];
    float* out = (float*)d_out;

    char* ws = (char*)d_ws;
    auto alloc = [&](size_t bytes) {
        char* p = ws;
        ws += (bytes + 255) & ~(size_t)255;
        return p;
    };
    unsigned char* x_f8    = (unsigned char*)alloc((size_t)Mrows * Dsz);          //  8 MB
    unsigned char* inw_f8  = (unsigned char*)alloc((size_t)2 * Esz * Dsz);        //  4 MB
    unsigned char* dtw_f8  = (unsigned char*)alloc((size_t)Esz * Esz);            //  4 MB
    unsigned char* outw_f8 = (unsigned char*)alloc((size_t)Dsz * Esz);            //  2 MB
    __hip_bfloat16* xp_bf  = (__hip_bfloat16*)alloc((size_t)Mrows * 2 * Esz * 2); // 64 MB
    __hip_bfloat16* xc_bf  = (__hip_bfloat16*)alloc((size_t)Mrows * Esz * 2);     // 32 MB
    unsigned char* xc_f8   = (unsigned char*)alloc((size_t)Mrows * Esz);          // 16 MB
    unsigned char* s_f8    = (unsigned char*)alloc((size_t)Mrows * Esz);          // 16 MB
    __hip_bfloat16* wb_bf  = (__hip_bfloat16*)alloc((size_t)48 * Esz * 2);
    float* rowsum = (float*)alloc(Mrows * 4);
    float* u_buf  = (float*)alloc((size_t)Mrows * Ssz * 4);
    float* ct_buf = (float*)alloc((size_t)Mrows * Ssz * 4);
    float* ys_buf = (float*)alloc(Mrows * 4);
    (void)alloc(131072);           // pad: fp8 tail over-reads stay inside ws

    hipMemsetAsync(rowsum, 0, Mrows * 4, stream);

    cvt_all<<<4608, 256, 0, stream>>>((const float4*)x, (const float4*)in_w,
                                      (const float4*)dt_w, (const float4*)out_w,
                                      (int*)x_f8, (int*)inw_f8, (int*)dtw_f8,
                                      (int*)outw_f8);
    pack_bcd<<<48 * Esz / 256, 256, 0, stream>>>(B_w, C_w, D_w, wb_bf);

    // GEMM1 (256² 4-phase): xp = x @ in_w^T + in_b  (8192x4096x1024) -> bf16
    gemm256<0, 127, 121, 1024, 4096><<<dim3(16, 32), 512, 0, stream>>>(
        x_f8, inw_f8, in_b, xp_bf, nullptr);

    conv_gate_k<<<(Mrows * Esz / 8) / 256, 256, 0, stream>>>(
        xp_bf, conv_w, conv_b, xc_bf, (int2*)xc_f8, (int2*)s_f8);

    // GEMM2 (256² 4-phase): softplus(xc @ dt_w^T + dt_b) row-sums (8192x2048x2048)
    gemm256<1, 123, 121, 2048, 2048><<<dim3(8, 32), 512, 0, stream>>>(
        xc_f8, dtw_f8, dt_b, nullptr, rowsum);

    bcd_mfma<<<Mrows / 64, 256, 0, stream>>>(xc_bf, wb_bf, B_b, C_b, D_b, u_buf, ct_buf);

    scan_k<<<Bsz, 256, 0, stream>>>(rowsum, u_buf, ct_buf, ys_buf);

    // GEMM3 (128² 2-phase, proven): out = x + ys[row]*(S @ out_w^T) + out_b
    gemm_f8_sm<123, 121><<<dim3(Dsz / 128, Mrows / 128), 256, 0, stream>>>(
        s_f8, outw_f8, out_b, Mrows, Dsz, Esz, x, ys_buf, out);
}

// Round 4
// 442.459 us; speedup vs baseline: 1.0113x; 1.0113x over previous
//
#include <hip/hip_runtime.h>
#include <hip/hip_bf16.h>

// Problem constants
#define Bsz 4
#define Tsz 2048
#define Dsz 1024
#define Ssz 16
#define Esz 2048
#define Mrows (Bsz*Tsz)        // 8192

typedef __attribute__((ext_vector_type(8))) short short8;
typedef __attribute__((ext_vector_type(4))) float floatx4;
typedef __attribute__((ext_vector_type(16))) float floatx16;
typedef __attribute__((ext_vector_type(8))) int int8v;
typedef __attribute__((ext_vector_type(4))) int int4v;

#define ZERO16 (floatx16){0.f,0.f,0.f,0.f,0.f,0.f,0.f,0.f,0.f,0.f,0.f,0.f,0.f,0.f,0.f,0.f}

__device__ __forceinline__ void async_ld16(const void* g, void* l) {
    __builtin_amdgcn_global_load_lds(
        (const __attribute__((address_space(1))) void*)g,
        (__attribute__((address_space(3))) void*)l,
        16, 0, 0);
}

__device__ __forceinline__ float sigmoidf_(float v) { return 1.f / (1.f + expf(-v)); }
__device__ __forceinline__ float bf2f(unsigned short u) {
    union { unsigned u32; float f; } c; c.u32 = (unsigned)u << 16; return c.f;
}
__device__ __forceinline__ int pk_fp8x4(float a, float b, float c, float d) {
    int lo = __builtin_amdgcn_cvt_pk_fp8_f32(a, b, 0, 0);
    int hi = __builtin_amdgcn_cvt_pk_fp8_f32(c, d, 0, 0);
    return (lo & 0xFFFF) | (hi << 16);
}

// s_waitcnt immediates (gfx9): vm[3:0]|exp[6:4]|lgkm[11:8]|vm[15:14]
#define WAIT_VM(N)   (0xF70 | (N))

// ---------------------------------------------------------------------------
// merged conversions: x -> fp8 (x1), in_w -> fp8 (x64), dt_w -> fp8 (x64),
// out_w -> fp8 (x64).
// ---------------------------------------------------------------------------
#define CV_S0 2097152   // x:     8388608 f32 / 4
#define CV_S1 3145728   // in_w: +4194304 / 4
#define CV_S2 4194304   // dt_w: +4194304 / 4
#define CV_S3 4718592   // out_w:+2097152 / 4
__global__ void cvt_all(const float4* __restrict__ x,  const float4* __restrict__ iw,
                        const float4* __restrict__ dw, const float4* __restrict__ ow,
                        int* __restrict__ x8, int* __restrict__ iw8,
                        int* __restrict__ dw8, int* __restrict__ ow8) {
    int i = blockIdx.x * blockDim.x + threadIdx.x;
    const int stride = gridDim.x * blockDim.x;
    for (; i < CV_S3; i += stride) {
        if (i < CV_S0) {
            float4 v = x[i];
            x8[i] = pk_fp8x4(v.x, v.y, v.z, v.w);
        } else if (i < CV_S1) {
            const int j = i - CV_S0;
            float4 v = iw[j];
            iw8[j] = pk_fp8x4(v.x * 64.f, v.y * 64.f, v.z * 64.f, v.w * 64.f);
        } else if (i < CV_S2) {
            const int j = i - CV_S1;
            float4 v = dw[j];
            dw8[j] = pk_fp8x4(v.x * 64.f, v.y * 64.f, v.z * 64.f, v.w * 64.f);
        } else {
            const int j = i - CV_S2;
            float4 v = ow[j];
            ow8[j] = pk_fp8x4(v.x * 64.f, v.y * 64.f, v.z * 64.f, v.w * 64.f);
        }
    }
}

// ---------------------------------------------------------------------------
// MX-fp8 GEMM via 32x32x64 MFMA.  R4: four schedule variants all pinned at
// ~600 TF with VALUBusy == 4.75 x MfmaUtil invariant -> per-MFMA-call VALU
// overhead is the binding cost, not the schedule.  32x32x64 = 131072 FLOP
// per call (2x the 16x16x128) at the same ubench rate (4686 TF, m59):
// same FLOPs in HALF the calls.  Structure = proven R2 compiler-scheduled
// loop: 128x128 tile, BK=128B, 4 waves 2x2, per-wave 64x64 via 2x2 accs of
// 32x32(f32x16); 2-stage LDS, one vmcnt(0)+barrier per K-tile.
// Operand layout (derived from the verified 16x16x128 family):
//   A: row = lane&31 (+32*mi), k = (lane>>5)*32 + [0:32)  (2 x b128)
//   B: col = lane&31 (+32*nj), same k slices
//   C/D: col = lane&31, row = (reg&3) + 8*(reg>>2) + 4*(lane>>5)  [m74/m101]
// MODE: 0 bf16 store+bias, 1 softplus rowsum.
// ---------------------------------------------------------------------------
template<int MODE, int SA, int SB>
__launch_bounds__(256, 2)
__global__ void gemm32_f8(const unsigned char* __restrict__ A,
                          const unsigned char* __restrict__ Bw,
                          const float* __restrict__ bias,
                          int M, int N, int K,
                          __hip_bfloat16* __restrict__ outb,
                          float* __restrict__ rowsum) {
    __shared__ __align__(16) unsigned char sA[2 * 16384];  // 128 rows x 128B
    __shared__ __align__(16) unsigned char sB[2 * 16384];

    const int tid  = threadIdx.x;
    const int wave = tid >> 6, lane = tid & 63;
    const int wm = wave >> 1, wn = wave & 1;
    const int hi = lane >> 5, l31 = lane & 31, l7 = lane & 7;

    // XCD-aware remap: each XCD owns a contiguous M-stripe (nwg % 8 == 0).
    const int gx = gridDim.x, gy = gridDim.y;
    const int flat = blockIdx.y * gx + blockIdx.x;
    const int stripe = gy >> 3;
    const int xcd = flat & 7, local = flat >> 3;
    const int mt = xcd * stripe + (local % stripe);
    const int nt = local / stripe;
    const int m0 = mt * 128, n0 = nt * 128;

    floatx16 acc00 = ZERO16, acc01 = ZERO16, acc10 = ZERO16, acc11 = ZERO16;

    // staging: A 16KB (4 instr/wave), B 16KB (4 instr/wave);
    // LDS slot s of row r holds global 16B chunk s^(r&7).
    const unsigned char* pa[4];
    const unsigned char* pb[4];
#pragma unroll
    for (int i = 0; i < 4; ++i) {
        const int idx = i * 256 + tid, row = idx >> 3, s = idx & 7;
        pa[i] = A + (size_t)(m0 + row) * K + ((s ^ (row & 7)) * 16);
        pb[i] = Bw + (size_t)(n0 + row) * K + ((s ^ (row & 7)) * 16);
    }

    // fragment read offsets: frag row = wm*64 + mi*32 + l31 (row&7 == l7);
    // k-sub s part p -> chunk s*4 + hi*2 + p, at slot chunk^(row&7).
    const int rbA = (wm * 64 + l31) * 128;   // + mi*4096
    const int rbB = (wn * 64 + l31) * 128;   // + nj*4096
    int ch[2][2];
#pragma unroll
    for (int s = 0; s < 2; ++s)
#pragma unroll
        for (int p = 0; p < 2; ++p)
            ch[s][p] = (((s << 2) + (hi << 1) + p) ^ l7) << 4;

#define F8_ISSUE(ST) do {                                                      \
        _Pragma("unroll")                                                      \
        for (int i = 0; i < 4; ++i) {                                          \
            async_ld16(pa[i], &sA[(ST) * 16384 + (i * 256 + wave * 64) * 16]); \
            pa[i] += 128;                                                      \
        }                                                                      \
        _Pragma("unroll")                                                      \
        for (int i = 0; i < 4; ++i) {                                          \
            async_ld16(pb[i], &sB[(ST) * 16384 + (i * 256 + wave * 64) * 16]); \
            pb[i] += 128;                                                      \
        }                                                                      \
    } while (0)

#define RD32(dst, buf, off) do {                                               \
        int4v lo_ = *(const int4v*)&(buf)[off];                                \
        int4v hi_ = *(const int4v*)&(buf)[(off) + 16 - (((off) & 16) << 1)     \
                                          + ((ch[s_][1] - ch[s_][0]))];        \
        (void)hi_; } while (0)
#undef RD32

    const int ntile = K >> 7;      // K-tiles of 128B
    F8_ISSUE(0);                   // tile 0 -> stage 0
    for (int kt = 0; kt < ntile; ++kt) {
        const int st = kt & 1;
        const int base = st * 16384;
        __builtin_amdgcn_s_waitcnt(WAIT_VM(0));   // own tile-kt loads landed
        __syncthreads();                          // all waves: landed + prev reads done
        F8_ISSUE(st ^ 1);          // prefetch tile kt+1 (tail: garbage into ws pad)

#pragma unroll
        for (int s = 0; s < 2; ++s) {
            int8v aF0, aF1, bF0, bF1;
            {
                int4v lo = *(const int4v*)&sA[base + rbA + ch[s][0]];
                int4v h4 = *(const int4v*)&sA[base + rbA + ch[s][1]];
                aF0 = __builtin_shufflevector(lo, h4, 0, 1, 2, 3, 4, 5, 6, 7);
            }
            {
                int4v lo = *(const int4v*)&sA[base + rbA + 4096 + ch[s][0]];
                int4v h4 = *(const int4v*)&sA[base + rbA + 4096 + ch[s][1]];
                aF1 = __builtin_shufflevector(lo, h4, 0, 1, 2, 3, 4, 5, 6, 7);
            }
            {
                int4v lo = *(const int4v*)&sB[base + rbB + ch[s][0]];
                int4v h4 = *(const int4v*)&sB[base + rbB + ch[s][1]];
                bF0 = __builtin_shufflevector(lo, h4, 0, 1, 2, 3, 4, 5, 6, 7);
            }
            {
                int4v lo = *(const int4v*)&sB[base + rbB + 4096 + ch[s][0]];
                int4v h4 = *(const int4v*)&sB[base + rbB + 4096 + ch[s][1]];
                bF1 = __builtin_shufflevector(lo, h4, 0, 1, 2, 3, 4, 5, 6, 7);
            }
            acc00 = __builtin_amdgcn_mfma_scale_f32_32x32x64_f8f6f4(
                aF0, bF0, acc00, 0, 0, 0, SA, 0, SB);
            acc01 = __builtin_amdgcn_mfma_scale_f32_32x32x64_f8f6f4(
                aF0, bF1, acc01, 0, 0, 0, SA, 0, SB);
            acc10 = __builtin_amdgcn_mfma_scale_f32_32x32x64_f8f6f4(
                aF1, bF0, acc10, 0, 0, 0, SA, 0, SB);
            acc11 = __builtin_amdgcn_mfma_scale_f32_32x32x64_f8f6f4(
                aF1, bF1, acc11, 0, 0, 0, SA, 0, SB);
        }
    }
#undef F8_ISSUE
    __builtin_amdgcn_s_waitcnt(WAIT_VM(0));       // drain garbage tail tile

    // epilogue: C/D col = lane&31, row = (reg&3) + 8*(reg>>2) + 4*hi
    if (MODE == 0) {
#define ST32(ACC, MI, NJ) do {                                                 \
        const int col = n0 + wn * 64 + (NJ) * 32 + l31;                        \
        const float bc = bias[col];                                            \
        const int rowb = m0 + wm * 64 + (MI) * 32 + 4 * hi;                    \
        _Pragma("unroll")                                                      \
        for (int r = 0; r < 16; ++r) {                                         \
            const int row = rowb + (r & 3) + 8 * (r >> 2);                     \
            outb[(size_t)row * N + col] = __float2bfloat16(ACC[r] + bc);       \
        }                                                                      \
    } while (0)
        ST32(acc00, 0, 0); ST32(acc01, 0, 1);
        ST32(acc10, 1, 0); ST32(acc11, 1, 1);
#undef ST32
    } else {
        const int col0 = n0 + wn * 64 + l31;
        const float bc0 = bias[col0], bc1 = bias[col0 + 32];
#define RSUM(MI, A0, A1) do {                                                  \
        const int rowb = m0 + wm * 64 + (MI) * 32 + 4 * hi;                    \
        _Pragma("unroll")                                                      \
        for (int r = 0; r < 16; ++r) {                                         \
            float v0 = A0[r] + bc0;                                            \
            float v1 = A1[r] + bc1;                                            \
            float sp = ((v0 > 20.f) ? v0 : log1pf(expf(v0)))                   \
                     + ((v1 > 20.f) ? v1 : log1pf(expf(v1)));                  \
            sp += __shfl_xor(sp, 1);  sp += __shfl_xor(sp, 2);                 \
            sp += __shfl_xor(sp, 4);  sp += __shfl_xor(sp, 8);                 \
            sp += __shfl_xor(sp, 16);                                          \
            if (l31 == 0)                                                      \
                atomicAdd(&rowsum[rowb + (r & 3) + 8 * (r >> 2)], sp);         \
        }                                                                      \
    } while (0)
        RSUM(0, acc00, acc01);
        RSUM(1, acc10, acc11);
#undef RSUM
    }
}

// ---------------------------------------------------------------------------
// 128x128 2-phase 16x16x128 MX-fp8 GEMM (proven R2 loop) — GEMM3 only
// (fp32 resid + ys[row]*acc + bias epilogue), kept for isolation of the
// 32x32 layout change.
// ---------------------------------------------------------------------------
template<int SA, int SB>
__launch_bounds__(256, 2)
__global__ void gemm_f8_sm(const unsigned char* __restrict__ A,
                           const unsigned char* __restrict__ Bw,
                           const float* __restrict__ bias,
                           int M, int N, int K,
                           const float* __restrict__ resid,
                           const float* __restrict__ ysv,
                           float* __restrict__ outf) {
    __shared__ __align__(16) unsigned char sA[2 * 16384];
    __shared__ __align__(16) unsigned char sB[2 * 16384];

    const int tid  = threadIdx.x;
    const int wave = tid >> 6, lane = tid & 63;
    const int wm = wave >> 1, wn = wave & 1;
    const int q = lane >> 4, lr = lane & 15;

    const int gx = gridDim.x, gy = gridDim.y;
    const int flat = blockIdx.y * gx + blockIdx.x;
    const int stripe = gy >> 3;
    const int xcd = flat & 7, local = flat >> 3;
    const int mt = xcd * stripe + (local % stripe);
    const int nt = local / stripe;
    const int m0 = mt * 128, n0 = nt * 128;

    floatx4 acc[4][4];
#pragma unroll
    for (int i = 0; i < 4; ++i)
#pragma unroll
        for (int j = 0; j < 4; ++j) acc[i][j] = (floatx4){0.f, 0.f, 0.f, 0.f};

    const unsigned char* pa[4];
    const unsigned char* pb[4];
#pragma unroll
    for (int i = 0; i < 4; ++i) {
        const int idx = i * 256 + tid, row = idx >> 3, s = idx & 7;
        pa[i] = A + (size_t)(m0 + row) * K + ((s ^ (row & 7)) * 16);
        pb[i] = Bw + (size_t)(n0 + row) * K + ((s ^ (row & 7)) * 16);
    }

    const int rA = wm * 64 + lr, rB = wn * 64 + lr;
    const int oA0 = rA * 128 + (((2 * q)     ^ (rA & 7)) * 16);
    const int oA1 = rA * 128 + (((2 * q + 1) ^ (rA & 7)) * 16);
    const int oB0 = rB * 128 + (((2 * q)     ^ (rB & 7)) * 16);
    const int oB1 = rB * 128 + (((2 * q + 1) ^ (rB & 7)) * 16);

#define F8_ISSUE(ST) do {                                                      \
        _Pragma("unroll")                                                      \
        for (int i = 0; i < 4; ++i) {                                          \
            async_ld16(pa[i], &sA[(ST) * 16384 + (i * 256 + wave * 64) * 16]); \
            pa[i] += 128;                                                      \
        }                                                                      \
        _Pragma("unroll")                                                      \
        for (int i = 0; i < 4; ++i) {                                          \
            async_ld16(pb[i], &sB[(ST) * 16384 + (i * 256 + wave * 64) * 16]); \
            pb[i] += 128;                                                      \
        }                                                                      \
    } while (0)

    const int ntile = K >> 7;
    F8_ISSUE(0);
    for (int kt = 0; kt < ntile; ++kt) {
        const int st = kt & 1;
        __builtin_amdgcn_s_waitcnt(WAIT_VM(0));
        __syncthreads();
        F8_ISSUE(st ^ 1);

        int8v a8[4], b8[4];
#pragma unroll
        for (int i = 0; i < 4; ++i) {
            int4v lo = *(const int4v*)&sA[st * 16384 + oA0 + i * 2048];
            int4v hi = *(const int4v*)&sA[st * 16384 + oA1 + i * 2048];
            a8[i] = __builtin_shufflevector(lo, hi, 0, 1, 2, 3, 4, 5, 6, 7);
        }
#pragma unroll
        for (int j = 0; j < 4; ++j) {
            int4v lo = *(const int4v*)&sB[st * 16384 + oB0 + j * 2048];
            int4v hi = *(const int4v*)&sB[st * 16384 + oB1 + j * 2048];
            b8[j] = __builtin_shufflevector(lo, hi, 0, 1, 2, 3, 4, 5, 6, 7);
        }
#pragma unroll
        for (int i = 0; i < 4; ++i)
#pragma unroll
            for (int j = 0; j < 4; ++j)
                acc[i][j] = __builtin_amdgcn_mfma_scale_f32_16x16x128_f8f6f4(
                    a8[i], b8[j], acc[i][j], 0, 0, 0, SA, 0, SB);
    }
#undef F8_ISSUE
    __builtin_amdgcn_s_waitcnt(WAIT_VM(0));

#pragma unroll
    for (int i = 0; i < 4; ++i) {
        const int row = m0 + wm * 64 + i * 16 + q * 4;
#pragma unroll
        for (int j = 0; j < 4; ++j) {
            const int col = n0 + wn * 64 + j * 16 + lr;
            const float bc = bias[col];
#pragma unroll
            for (int r = 0; r < 4; ++r) {
                const size_t idx = (size_t)(row + r) * N + col;
                outf[idx] = resid[idx] + ysv[row + r] * acc[i][j][r] + bc;
            }
        }
    }
}

// ---------------------------------------------------------------------------
// fused elementwise pass over xp: depthwise conv(k=3)+bias+SiLU on main half
// -> xc (bf16) + xc*16 (fp8); SiLU on gate half -> S*16 (fp8).
// ---------------------------------------------------------------------------
__global__ void conv_gate_k(const __hip_bfloat16* __restrict__ xp,
                            const float* __restrict__ cw,
                            const float* __restrict__ cb,
                            __hip_bfloat16* __restrict__ xc,
                            int2* __restrict__ xc8,
                            int2* __restrict__ s8) {
    const int idx8 = blockIdx.x * blockDim.x + threadIdx.x;
    const int e = (idx8 & (Esz / 8 - 1)) * 8;
    const int r = idx8 >> 8;
    const int t = r & (Tsz - 1);
    const unsigned short* row0 = (const unsigned short*)(xp + (size_t)r * (2 * Esz) + e);
    short8 vm1 = (t > 0)       ? *(const short8*)(row0 - 2 * Esz) : (short8){0,0,0,0,0,0,0,0};
    short8 v00 = *(const short8*)row0;
    short8 vp1 = (t < Tsz - 1) ? *(const short8*)(row0 + 2 * Esz) : (short8){0,0,0,0,0,0,0,0};
    short8 o;
    float sil[8];
#pragma unroll
    for (int k = 0; k < 8; ++k) {
        const int ek = e + k;
        float v = bf2f((unsigned short)vm1[k]) * cw[ek * 3 + 0]
                + bf2f((unsigned short)v00[k]) * cw[ek * 3 + 1]
                + bf2f((unsigned short)vp1[k]) * cw[ek * 3 + 2] + cb[ek];
        sil[k] = v * sigmoidf_(v);
        __hip_bfloat16 h = __float2bfloat16(sil[k]);
        o[k] = *(short*)&h;
    }
    *(short8*)(xc + (size_t)idx8 * 8) = o;
    int2 p;
    p.x = pk_fp8x4(sil[0] * 16.f, sil[1] * 16.f, sil[2] * 16.f, sil[3] * 16.f);
    p.y = pk_fp8x4(sil[4] * 16.f, sil[5] * 16.f, sil[6] * 16.f, sil[7] * 16.f);
    xc8[idx8] = p;

    short8 g = *(const short8*)(row0 + Esz);
    float sg[8];
#pragma unroll
    for (int k = 0; k < 8; ++k) {
        const float gv = bf2f((unsigned short)g[k]);
        sg[k] = gv * sigmoidf_(gv);
    }
    int2 ps;
    ps.x = pk_fp8x4(sg[0] * 16.f, sg[1] * 16.f, sg[2] * 16.f, sg[3] * 16.f);
    ps.y = pk_fp8x4(sg[4] * 16.f, sg[5] * 16.f, sg[6] * 16.f, sg[7] * 16.f);
    s8[idx8] = ps;
}

// ---------------------------------------------------------------------------
// pack B_w/C_w/D_w (each [16,2048] fp32) into Wb [48,2048] bf16
// ---------------------------------------------------------------------------
__global__ void pack_bcd(const float* __restrict__ Bw, const float* __restrict__ Cw,
                         const float* __restrict__ Dw, __hip_bfloat16* __restrict__ Wb) {
    const int idx = blockIdx.x * blockDim.x + threadIdx.x;
    if (idx >= 48 * Esz) return;
    const int row = idx >> 11, col = idx & (Esz - 1);
    float v;
    if (row < 16)      v = Bw[row * Esz + col];
    else if (row < 32) v = Cw[(row - 16) * Esz + col];
    else               v = Dw[(row - 32) * Esz + col];
    Wb[idx] = __float2bfloat16(v);
}

// ---------------------------------------------------------------------------
// B/C/D projections via MFMA skinny GEMM: xc[M,E] @ Wb[48,E]^T.
// ---------------------------------------------------------------------------
__launch_bounds__(256)
__global__ void bcd_mfma(const __hip_bfloat16* __restrict__ xc,
                         const __hip_bfloat16* __restrict__ Wb,
                         const float* __restrict__ Bb, const float* __restrict__ Cb,
                         const float* __restrict__ Db,
                         float* __restrict__ u, float* __restrict__ Ct) {
    __shared__ __align__(16) __hip_bfloat16 sA[64 * 32];
    __shared__ __align__(16) __hip_bfloat16 sW[48 * 32];
    const int tid = threadIdx.x;
    const int wave = tid >> 6, lane = tid & 63;
    const int q = lane >> 4, lr = lane & 15;
    const int m0 = blockIdx.x * 64;

    floatx4 acc[3];
#pragma unroll
    for (int j = 0; j < 3; ++j) acc[j] = (floatx4){0.f, 0.f, 0.f, 0.f};

    const int ra = wave * 16 + (lane >> 2);
    const int ca = (lane & 3) * 8;

    for (int kt = 0; kt < (Esz >> 5); ++kt) {
        const int k0 = kt << 5;
        __syncthreads();
        async_ld16(&xc[(size_t)(m0 + ra) * Esz + k0 + ca], &sA[wave * 512]);
        if (wave < 3)
            async_ld16(&Wb[(size_t)ra * Esz + k0 + ca], &sW[wave * 512]);
        __syncthreads();

        short8 af = *(const short8*)&sA[(wave * 16 + lr) * 32 + q * 8];
#pragma unroll
        for (int j = 0; j < 3; ++j) {
            short8 wf = *(const short8*)&sW[(j * 16 + lr) * 32 + q * 8];
            acc[j] = __builtin_amdgcn_mfma_f32_16x16x32_bf16(af, wf, acc[j], 0, 0, 0);
        }
    }

    const int row = m0 + wave * 16 + q * 4;
    const float bb = Bb[lr], cbv = Cb[lr], db = Db[lr];
#pragma unroll
    for (int r = 0; r < 4; ++r) {
        const float bt = acc[0][r] + bb;
        const float ct = acc[1][r] + cbv;
        const float dt = acc[2][r] + db;
        u [(size_t)(row + r) * Ssz + lr] = bt * dt;
        Ct[(size_t)(row + r) * Ssz + lr] = ct;
    }
}

// ---------------------------------------------------------------------------
// Sequential SSM scan (decay computed inline from rowsum).  One block/batch.
// ---------------------------------------------------------------------------
__global__ void scan_k(const float* __restrict__ rowsum, const float* __restrict__ u,
                       const float* __restrict__ Ct, float* __restrict__ ys) {
    const int b = blockIdx.x;
    const int tid = threadIdx.x;
    const int lane = tid & 63, wave = tid >> 6;
    __shared__ __align__(16) float su[256 * Ssz];
    __shared__ __align__(16) float sc[256 * Ssz];
    __shared__ float sp[256 * 17];
    __shared__ float sd[256];
    float st = 0.f;
    for (int t0 = 0; t0 < Tsz; t0 += 256) {
        __syncthreads();
        const float4* ub = (const float4*)(u  + ((size_t)b * Tsz + t0) * Ssz);
        const float4* cb = (const float4*)(Ct + ((size_t)b * Tsz + t0) * Ssz);
#pragma unroll
        for (int i = 0; i < 4; ++i) {
            ((float4*)su)[tid + i * 256] = ub[tid + i * 256];
            ((float4*)sc)[tid + i * 256] = cb[tid + i * 256];
        }
        {
            const float m = rowsum[b * Tsz + t0 + tid] * (1.f / (float)Esz);
            sd[tid] = expf(fminf(fmaxf(-m, -10.f), 10.f));
        }
        __syncthreads();
        if (wave == 0 && lane < 16) {
#pragma unroll 8
            for (int i = 0; i < 256; ++i) {
                st = st * sd[i] + su[i * Ssz + lane];
                sp[i * 17 + lane] = sc[i * Ssz + lane] * st;
            }
        }
        __syncthreads();
        float s = 0.f;
#pragma unroll
        for (int j = 0; j < 16; ++j) s += sp[tid * 17 + j];
        ys[b * Tsz + t0 + tid] = s;
    }
}

// ---------------------------------------------------------------------------
extern "C" void kernel_launch(void* const* d_in, const int* in_sizes, int n_in,
                              void* d_out, int out_size, void* d_ws, size_t ws_size,
                              hipStream_t stream) {
    const float* x      = (const float*)d_in[0];
    const float* in_w   = (const float*)d_in[1];
    const float* in_b   = (const float*)d_in[2];
    const float* conv_w = (const float*)d_in[3];
    const float* conv_b = (const float*)d_in[4];
    const float* dt_w   = (const float*)d_in[5];
    const float* dt_b   = (const float*)d_in[6];
    const float* B_w    = (const float*)d_in[7];
    const float* B_b    = (const float*)d_in[8];
    const float* C_w    = (const float*)d_in[9];
    const float* C_b    = (const float*)d_in[10];
    const float* D_w    = (const float*)d_in[11];
    const float* D_b    = (const float*)d_in[12];
    const float* out_w  = (const float*)d_in[13];
    const float* out_b  = (const float*)d_in[14];
    float* out = (float*)d_out;

    char* ws = (char*)d_ws;
    auto alloc = [&](size_t bytes) {
        char* p = ws;
        ws += (bytes + 255) & ~(size_t)255;
        return p;
    };
    unsigned char* x_f8    = (unsigned char*)alloc((size_t)Mrows * Dsz);          //  8 MB
    unsigned char* inw_f8  = (unsigned char*)alloc((size_t)2 * Esz * Dsz);        //  4 MB
    unsigned char* dtw_f8  = (unsigned char*)alloc((size_t)Esz * Esz);            //  4 MB
    unsigned char* outw_f8 = (unsigned char*)alloc((size_t)Dsz * Esz);            //  2 MB
    __hip_bfloat16* xp_bf  = (__hip_bfloat16*)alloc((size_t)Mrows * 2 * Esz * 2); // 64 MB
    __hip_bfloat16* xc_bf  = (__hip_bfloat16*)alloc((size_t)Mrows * Esz * 2);     // 32 MB
    unsigned char* xc_f8   = (unsigned char*)alloc((size_t)Mrows * Esz);          // 16 MB
    unsigned char* s_f8    = (unsigned char*)alloc((size_t)Mrows * Esz);          // 16 MB
    __hip_bfloat16* wb_bf  = (__hip_bfloat16*)alloc((size_t)48 * Esz * 2);
    float* rowsum = (float*)alloc(Mrows * 4);
    float* u_buf  = (float*)alloc((size_t)Mrows * Ssz * 4);
    float* ct_buf = (float*)alloc((size_t)Mrows * Ssz * 4);
    float* ys_buf = (float*)alloc(Mrows * 4);
    (void)alloc(131072);           // pad: fp8 tail over-reads stay inside ws

    hipMemsetAsync(rowsum, 0, Mrows * 4, stream);

    cvt_all<<<4608, 256, 0, stream>>>((const float4*)x, (const float4*)in_w,
                                      (const float4*)dt_w, (const float4*)out_w,
                                      (int*)x_f8, (int*)inw_f8, (int*)dtw_f8,
                                      (int*)outw_f8);
    pack_bcd<<<48 * Esz / 256, 256, 0, stream>>>(B_w, C_w, D_w, wb_bf);

    // GEMM1 (32x32x64 MX-fp8): xp = x @ in_w^T + in_b  (8192x4096x1024) -> bf16
    // scales: A = x (2^0 -> 127), B = in_w*64 (2^-6 -> 121)
    gemm32_f8<0, 127, 121><<<dim3(4096 / 128, Mrows / 128), 256, 0, stream>>>(
        x_f8, inw_f8, in_b, Mrows, 4096, 1024, xp_bf, nullptr);

    conv_gate_k<<<(Mrows * Esz / 8) / 256, 256, 0, stream>>>(
        xp_bf, conv_w, conv_b, xc_bf, (int2*)xc_f8, (int2*)s_f8);

    // GEMM2 (32x32x64 MX-fp8): softplus(xc @ dt_w^T + dt_b) row-sums (8192x2048x2048)
    // scales: A = xc*16 (2^-4 -> 123), B = dt_w*64 (2^-6 -> 121)
    gemm32_f8<1, 123, 121><<<dim3(Esz / 128, Mrows / 128), 256, 0, stream>>>(
        xc_f8, dtw_f8, dt_b, Mrows, Esz, Esz, nullptr, rowsum);

    bcd_mfma<<<Mrows / 64, 256, 0, stream>>>(xc_bf, wb_bf, B_b, C_b, D_b, u_buf, ct_buf);

    scan_k<<<Bsz, 256, 0, stream>>>(rowsum, u_buf, ct_buf, ys_buf);

    // GEMM3 (16x16x128, proven): out = x + ys[row]*(S @ out_w^T) + out_b
    gemm_f8_sm<123, 121><<<dim3(Dsz / 128, Mrows / 128), 256, 0, stream>>>(
        s_f8, outw_f8, out_b, Mrows, Dsz, Esz, x, ys_buf, out);
}